// Round 2
// baseline (84.136 us; speedup 1.0000x reference)
//
#include <hip/hip_runtime.h>
#include <hip/hip_bf16.h>

// KeyedSensor encrypt->decrypt roundtrip.
// Algebra: invperm[perm[i]] == i, so
//   h_rec[:, i] = h[:, i] * scale[i] / scale[i] = h[:, i]
// => output is exactly x (fp32 rounding only). Pure 201 MB d2d copy.
//
// Copy tuned for MLP: 4 independent 16B loads in flight per thread
// (breaks the load->store dependency chain), non-temporal (streaming,
// zero reuse -> skip cache allocate).

typedef float f4 __attribute__((ext_vector_type(4)));

__global__ __launch_bounds__(256) void keyed_sensor_copy(
    const f4* __restrict__ src, f4* __restrict__ dst, long n4) {
    long i = (long)blockIdx.x * blockDim.x + threadIdx.x;
    long stride = (long)gridDim.x * blockDim.x;

    // Unrolled-by-4 grid-stride: 4 loads issued back-to-back, then 4 stores.
    long i4;
    for (i4 = i; i4 + 3 * stride < n4; i4 += 4 * stride) {
        f4 a = __builtin_nontemporal_load(&src[i4]);
        f4 b = __builtin_nontemporal_load(&src[i4 + stride]);
        f4 c = __builtin_nontemporal_load(&src[i4 + 2 * stride]);
        f4 d = __builtin_nontemporal_load(&src[i4 + 3 * stride]);
        __builtin_nontemporal_store(a, &dst[i4]);
        __builtin_nontemporal_store(b, &dst[i4 + stride]);
        __builtin_nontemporal_store(c, &dst[i4 + 2 * stride]);
        __builtin_nontemporal_store(d, &dst[i4 + 3 * stride]);
    }
    for (; i4 < n4; i4 += stride) {
        __builtin_nontemporal_store(__builtin_nontemporal_load(&src[i4]), &dst[i4]);
    }
}

extern "C" void kernel_launch(void* const* d_in, const int* in_sizes, int n_in,
                              void* d_out, int out_size, void* d_ws, size_t ws_size,
                              hipStream_t stream) {
    const float* x = (const float*)d_in[0];
    float* out = (float*)d_out;

    // out_size = N*C*H*W = 50,331,648; divisible by 4 (H*W = 65536).
    long n4 = (long)out_size / 4;  // 12,582,912 float4s

    const int block = 256;
    long blocks_needed = (n4 + block - 1) / block;
    int grid = (int)(blocks_needed < 2048 ? blocks_needed : 2048);

    keyed_sensor_copy<<<grid, block, 0, stream>>>(
        (const f4*)x, (f4*)out, n4);
}

// Round 3
// 81.156 us; speedup vs baseline: 1.0367x; 1.0367x over previous
//
#include <hip/hip_runtime.h>
#include <hip/hip_bf16.h>

// KeyedSensor encrypt->decrypt roundtrip.
// Algebra: invperm[perm[i]] == i, so
//   h_rec[:, i] = h[:, i] * scale[i] / scale[i] = h[:, i]
// => output is exactly x (fp32 rounding only). Pure 201 MB d2d copy.
//
// R2 post-mortem: hand-rolled float4 grid-stride copy = 4.79 TB/s (84 us),
// unroll/nontemporal neutral -> not an ILP problem. Try the runtime's tuned
// D2D blit (hipMemcpyAsync is graph-capturable and explicitly allowed) as
// the external known-good copy reference.

extern "C" void kernel_launch(void* const* d_in, const int* in_sizes, int n_in,
                              void* d_out, int out_size, void* d_ws, size_t ws_size,
                              hipStream_t stream) {
    const float* x = (const float*)d_in[0];
    // out_size = N*C*H*W = 50,331,648 floats = 201.3 MB
    size_t bytes = (size_t)out_size * sizeof(float);
    hipMemcpyAsync(d_out, x, bytes, hipMemcpyDeviceToDevice, stream);
}